// Round 10
// baseline (247.421 us; speedup 1.0000x reference)
//
#include <hip/hip_runtime.h>
#include <hip/hip_bf16.h>

#define BB 64
#define NN 2048
#define CC 64
#define EE 16
#define OO 64
#define JJ 4096  // BB*CC

typedef __attribute__((ext_vector_type(8))) short short8;
typedef __attribute__((ext_vector_type(4))) float f32x4;
typedef __attribute__((ext_vector_type(4))) unsigned short u16x4;
typedef __attribute__((ext_vector_type(8))) unsigned short u16x8;

__device__ __forceinline__ unsigned short f2bf(float f) {
  __hip_bfloat16 h = __float2bfloat16(f);
  return *reinterpret_cast<unsigned short*>(&h);
}
__device__ __forceinline__ float bf2f(unsigned short u) {
  unsigned int v = ((unsigned int)u) << 16;
  return *reinterpret_cast<float*>(&v);
}
__device__ __forceinline__ void gload16(const void* g, void* l) {
  __builtin_amdgcn_global_load_lds(
      (const __attribute__((address_space(1))) unsigned int*)g,
      (__attribute__((address_space(3))) unsigned int*)l, 16, 0, 0);
}

// ---------------- Kernel 1: Ab = bf16(softmax(relu(E E^T), axis=1)) ----------------
__global__ __launch_bounds__(256) void supports_kernel(
    const float* __restrict__ emb, unsigned short* __restrict__ A)
{
  int n = blockIdx.x;
  int tid = threadIdx.x;
  float en[EE];
#pragma unroll
  for (int d = 0; d < EE; ++d) en[d] = emb[n*EE + d];

  float logit[8];
  float lmax = 0.0f;  // relu >= 0
#pragma unroll
  for (int i = 0; i < 8; ++i) {
    int m = i*256 + tid;
    const float* em = emb + m*EE;
    float s = 0.f;
#pragma unroll
    for (int d = 0; d < EE; ++d) s = fmaf(en[d], em[d], s);
    s = fmaxf(s, 0.f);
    logit[i] = s;
    lmax = fmaxf(lmax, s);
  }
  __shared__ float red[256];
  red[tid] = lmax; __syncthreads();
  for (int s = 128; s > 0; s >>= 1) {
    if (tid < s) red[tid] = fmaxf(red[tid], red[tid+s]);
    __syncthreads();
  }
  lmax = red[0]; __syncthreads();
  float sum = 0.f;
#pragma unroll
  for (int i = 0; i < 8; ++i) {
    float e = __expf(logit[i]-lmax);
    logit[i] = e; sum += e;
  }
  red[tid] = sum; __syncthreads();
  for (int s = 128; s > 0; s >>= 1) {
    if (tid < s) red[tid] += red[tid+s];
    __syncthreads();
  }
  float inv = 1.f/red[0];
#pragma unroll
  for (int i = 0; i < 8; ++i) A[(size_t)n*NN + i*256 + tid] = f2bf(logit[i]*inv);
}

// ---------------- Kernel 1b: Xt[b*64+c][n] = bf16(x[b][n][c]) ----------------
__global__ __launch_bounds__(256) void xpose_kernel(
    const float* __restrict__ x, unsigned short* __restrict__ Xt)
{
  int b = blockIdx.y;        // 64
  int n0 = blockIdx.x * 64;  // 32
  __shared__ float T[64][65];
  int tid = threadIdx.x;
  int r = tid >> 4, c4 = (tid & 15) * 4;
  const float* src = x + ((size_t)b*NN + n0)*64;
#pragma unroll
  for (int rr = r; rr < 64; rr += 16) {
    float4 v = *(const float4*)(src + rr*64 + c4);
    T[rr][c4] = v.x; T[rr][c4+1] = v.y; T[rr][c4+2] = v.z; T[rr][c4+3] = v.w;
  }
  __syncthreads();
  int c = tid >> 2, q0 = (tid & 3) * 16;   // 16 bf16 per thread along n
  unsigned short* dst = Xt + ((size_t)b*64 + c)*NN + n0 + q0;
  u16x8 o0, o1;
#pragma unroll
  for (int q = 0; q < 8; ++q) o0[q] = f2bf(T[q0+q][c]);
#pragma unroll
  for (int q = 0; q < 8; ++q) o1[q] = f2bf(T[q0+8+q][c]);
  *(u16x8*)(dst) = o0;
  *(u16x8*)(dst + 8) = o1;
}

// ---------------- Kernel 2: bf16 MFMA GEMM (r6-proven), C[m][j] = sum_k A[m][k]*Bt[j][k] ----
// dbuf LDS + early STAGE + counted vmcnt(8); raw s_barrier.
// Crow stores are PRE-SWIZZLED for final_mfma's linear gload16 staging:
//   col' = jcol ^ ((jcol & 0x1C0) >> 3)   (bakes unit-swizzle (c>>3)^(b&7) into global)
__device__ __forceinline__ void stage_tile(
    const unsigned short* __restrict__ A, const unsigned short* __restrict__ Bt,
    unsigned short* as, unsigned short* bs,
    int m0, int j0, int k0, int wid, int lrow, int lu)
{
#pragma unroll
  for (int li = 0; li < 4; ++li) {
    int rb = wid*32 + li*8;
    int r = rb + lrow;
    int su = lu ^ (r & 7);
    gload16(A  + (size_t)(m0 + r)*2048 + k0 + su*8, as + rb*64);
    gload16(Bt + (size_t)(j0 + r)*2048 + k0 + su*8, bs + rb*64);
  }
}

__global__ __launch_bounds__(256) void gemm_bt_bf16(
    const unsigned short* __restrict__ A, const unsigned short* __restrict__ Bt,
    unsigned short* __restrict__ Crow, unsigned short* __restrict__ Ct, int writeT)
{
  __shared__ unsigned short As[2][128*64];  // [row][k], 16B-unit XOR swizzle, dbuf
  __shared__ unsigned short Bs[2][128*64];
  int tid = threadIdx.x;
  int bid = blockIdx.x;
  int swz = (bid & 7) * 64 + (bid >> 3);    // 512 blocks -> XCD-contiguous chunks
  int m0 = (swz >> 5) * 128, j0 = (swz & 31) * 128;
  int wid = tid >> 6, lane = tid & 63;
  int wm = wid >> 1, wn = wid & 1;          // 2x2 wave grid, 64x64 per wave
  int fr = lane & 15, kg = lane >> 4;
  int lrow = lane >> 3, lu = lane & 7;      // staging: 8 rows x 8 units per wave-load

  f32x4 acc[4][4];
#pragma unroll
  for (int i = 0; i < 4; ++i)
#pragma unroll
    for (int j = 0; j < 4; ++j) acc[i][j] = (f32x4){0.f,0.f,0.f,0.f};

  stage_tile(A, Bt, As[0], Bs[0], m0, j0, 0, wid, lrow, lu);

  int cur = 0;
#pragma unroll 2
  for (int k0 = 0; k0 < 2048; k0 += 64) {
    if (k0 + 64 < 2048) {
      stage_tile(A, Bt, As[cur^1], Bs[cur^1], m0, j0, k0 + 64, wid, lrow, lu);
      asm volatile("s_waitcnt vmcnt(8)" ::: "memory");  // prior tile landed; 8 prefetch in flight
    } else {
      asm volatile("s_waitcnt vmcnt(0)" ::: "memory");  // last tile: drain
    }
    __builtin_amdgcn_s_barrier();
    asm volatile("" ::: "memory");

    const unsigned short* asb = As[cur];
    const unsigned short* bsb = Bs[cur];
#pragma unroll
    for (int ks = 0; ks < 2; ++ks) {
      short8 af[4], bv[4];
#pragma unroll
      for (int i = 0; i < 4; ++i) {
        int r = wm*64 + i*16 + fr;
        int u = ((ks << 2) | kg) ^ (r & 7);
        af[i] = *(const short8*)((const char*)asb + r*128 + u*16);
      }
#pragma unroll
      for (int j = 0; j < 4; ++j) {
        int r = wn*64 + j*16 + fr;
        int u = ((ks << 2) | kg) ^ (r & 7);
        bv[j] = *(const short8*)((const char*)bsb + r*128 + u*16);
      }
#pragma unroll
      for (int i = 0; i < 4; ++i)
#pragma unroll
        for (int j = 0; j < 4; ++j)
          acc[i][j] = __builtin_amdgcn_mfma_f32_16x16x32_bf16(af[i], bv[j], acc[i][j], 0, 0, 0);
    }
    asm volatile("" ::: "memory");
    __builtin_amdgcn_s_barrier();
    cur ^= 1;
  }

  int mrow4 = (lane >> 4) * 4;
#pragma unroll
  for (int i = 0; i < 4; ++i) {
    int mbase = m0 + wm*64 + i*16 + mrow4;
#pragma unroll
    for (int j = 0; j < 4; ++j) {
      int jcol = j0 + wn*64 + j*16 + fr;
      f32x4 v = acc[i][j];
      if (writeT) {
        u16x4 pk = { f2bf(v[0]), f2bf(v[1]), f2bf(v[2]), f2bf(v[3]) };
        *(u16x4*)(Ct + (size_t)jcol*2048 + mbase) = pk;
      }
      int jc2 = jcol ^ ((jcol & 0x1C0) >> 3);   // pre-swizzle for final's gload16
      Crow[(size_t)(mbase+0)*4096 + jc2] = f2bf(v[0]);
      Crow[(size_t)(mbase+1)*4096 + jc2] = f2bf(v[1]);
      Crow[(size_t)(mbase+2)*4096 + jc2] = f2bf(v[2]);
      Crow[(size_t)(mbase+3)*4096 + jc2] = f2bf(v[3]);
    }
  }
}

// ---------------- Kernel 3a: Wtg[n][o][kc'] = bf16 dynamic weights, TRANSFORMED ----------------
// Chebyshev fold: W0' = W0 - W2, W1' = W1, W2' = 2*W2  (so out = x*W0' + y1*W1' + y2*W2').
// kc' pre-swizzled: unit u = kc>>3, u' = (u&~7)|((u&7)^(o&7)); elem kc&7 kept.
// 8 nodes/block; dense 128B store runs via LDS staging.
__global__ __launch_bounds__(256) void wgen_kernel(
    const float* __restrict__ emb, const float* __restrict__ wp,
    unsigned short* __restrict__ wtg)
{
  __shared__ unsigned short Wlds[8][64*72];  // 72 KB: [node][o*72 + slot*8 + e]
  __shared__ float e_s[8][16];
  int tid = threadIdx.x;
  int g = blockIdx.x, r = blockIdx.y;        // g: node group of 8, r: kc range (64 kc)
  int n0 = g*8;
  if (tid < 128) e_s[tid >> 4][tid & 15] = emb[n0*16 + tid];
  __syncthreads();
  int o = tid & 63, w = tid >> 6;
  float kscale = (r == 2) ? 2.f : 1.f;       // W2' = 2*W2
#pragma unroll 1
  for (int p = 0; p < 2; ++p) {
    int u = r*8 + p*4 + w;                   // global unit index
    float acc[8][8];                         // [node][q], all statically indexed
#pragma unroll
    for (int n = 0; n < 8; ++n)
#pragma unroll
      for (int q = 0; q < 8; ++q) acc[n][q] = 0.f;
    const float* wpp = wp + u*512 + o;       // wp[d][u*8+q][o]
#pragma unroll
    for (int d = 0; d < 16; ++d) {
      float wv[8];
#pragma unroll
      for (int q = 0; q < 8; ++q) {
        float v = wpp[d*12288 + q*64];
        if (r == 0) v -= wpp[d*12288 + q*64 + 8192];   // W0' = W0 - W2 (kc+128)
        wv[q] = v;
      }
#pragma unroll
      for (int n = 0; n < 8; ++n) {
        float en = e_s[n][d];
#pragma unroll
        for (int q = 0; q < 8; ++q) acc[n][q] = fmaf(en, wv[q], acc[n][q]);
      }
    }
    int slot = (u & 7) ^ (o & 7);            // pre-baked final_mfma swizzle
#pragma unroll
    for (int n = 0; n < 8; ++n) {
      u16x8 pk;
#pragma unroll
      for (int q = 0; q < 8; ++q) pk[q] = f2bf(acc[n][q] * kscale);
      *(u16x8*)&Wlds[n][o*72 + slot*8] = pk;
    }
  }
  __syncthreads();
  // store phase: thread (nd, o) writes one contiguous 128B global run; 2 halves
#pragma unroll
  for (int half = 0; half < 2; ++half) {
    int nd = half*4 + (tid >> 6);
    unsigned short* dst = wtg + (size_t)(n0+nd)*12288 + o*192 + r*64;
#pragma unroll
    for (int s = 0; s < 8; ++s)
      *(u16x8*)(dst + s*8) = *(const u16x8*)&Wlds[nd][o*72 + s*8];
  }
}

// ---------------- Kernel 3b: per-node MFMA grouped GEMM (simple, 1 node/block) ----------------
// out[b,n,o] = sum_kc [x | y1 | y2][b][kc] * W'_n[kc][o] + bias_n[o]
// As = 3 planes [64 b][64 kc'] bf16: plane0 = x (reg+cvt, XOR ds_write),
// planes 1,2 = y1,y2 via gload16 (pre-swizzled in global by gemm epilogue).
// 48 KB LDS -> 3 blocks/CU; cross-block overlap hides the staging drain.
__global__ __launch_bounds__(256) void final_mfma(
    const float* __restrict__ x, const float* __restrict__ emb,
    const float* __restrict__ bp, const unsigned short* __restrict__ wtg,
    const unsigned short* __restrict__ y1, const unsigned short* __restrict__ y2,
    float* __restrict__ out)
{
  __shared__ unsigned short As[3*4096];     // 24 KB: [plane][b][64 kc']
  __shared__ unsigned short Ws[12288];      // 24 KB: [o][192 kc']
  int tid = threadIdx.x;
  int lane = tid & 63, wid = tid >> 6;
  int fr = lane & 15, kg = lane >> 4;
  int o = wid*16 + fr;
  int n = blockIdx.x;

  // -- Ws: 6 gload16/thread (Wtg pre-swizzled, linear copy) --
#pragma unroll
  for (int t = 0; t < 6; ++t) {
    int base = wid*3072 + t*512;            // bf16 units, wave-uniform
    gload16(wtg + (size_t)n*12288 + base + lane*8, &Ws[base]);
  }
  // -- As planes 1,2 (y1, y2): 2 gload16/thread each, pre-swizzled source --
#pragma unroll
  for (int t = 0; t < 2; ++t) {
    int base = wid*512 + t*2048;            // covers 0..4095 across 4 waves x 2
    gload16(y1 + (size_t)n*JJ + base + lane*8, &As[4096 + base]);
    gload16(y2 + (size_t)n*JJ + base + lane*8, &As[8192 + base]);
  }
  // -- As plane 0 (x): reg-load f32, cvt, XOR-swizzled ds_write --
  int b = tid & 63, q = tid >> 6;
#pragma unroll
  for (int h = 0; h < 2; ++h) {
    int ul = q + h*4;                       // unit 0..7
    const float* xp = x + ((size_t)b*NN + n)*64 + ul*8;
    float4 v0 = *(const float4*)xp;
    float4 v1 = *(const float4*)(xp + 4);
    float fx[8] = {v0.x,v0.y,v0.z,v0.w,v1.x,v1.y,v1.z,v1.w};
    u16x8 xb;
#pragma unroll
    for (int e = 0; e < 8; ++e) xb[e] = f2bf(fx[e]);
    *(u16x8*)&As[b*64 + (ul ^ (b & 7))*8] = xb;
  }
  __syncthreads();   // drains vmcnt+lgkmcnt (compiler full barrier)

  // -- bias into accumulator init --
  float breg = 0.f;
#pragma unroll
  for (int d = 0; d < 16; ++d) breg = fmaf(emb[n*16 + d], bp[d*64 + o], breg);
  f32x4 acc[4];
#pragma unroll
  for (int k = 0; k < 4; ++k) acc[k] = (f32x4){breg, breg, breg, breg};

  // -- grouped GEMM: M=64(b) x N=16(o per wave) x K=192 --
#pragma unroll
  for (int ks = 0; ks < 6; ++ks) {
    int u = ks*4 + kg;                      // global unit 0..23
    int p = u >> 3, uu = u & 7;
    short8 bv = *(const short8*)&Ws[o*192 + ((u & ~7) | (uu ^ (o & 7)))*8];
#pragma unroll
    for (int k = 0; k < 4; ++k) {
      int ra = k*16 + fr;
      short8 af = *(const short8*)&As[p*4096 + ra*64 + (uu ^ (ra & 7))*8];
      acc[k] = __builtin_amdgcn_mfma_f32_16x16x32_bf16(af, bv, acc[k], 0, 0, 0);
    }
  }
  // -- epilogue: col=lane&15 -> o, row=(lane>>4)*4+reg -> b --
  int mrow = (lane >> 4) * 4;
#pragma unroll
  for (int k = 0; k < 4; ++k) {
#pragma unroll
    for (int rr = 0; rr < 4; ++rr) {
      int brow = k*16 + mrow + rr;
      out[((size_t)brow*NN + n)*64 + o] = acc[k][rr];
    }
  }
}

extern "C" void kernel_launch(void* const* d_in, const int* in_sizes, int n_in,
                              void* d_out, int out_size, void* d_ws, size_t ws_size,
                              hipStream_t stream) {
  const float* x   = (const float*)d_in[0];   // [64, 2048, 64]
  const float* emb = (const float*)d_in[1];   // [2048, 16]
  const float* wp  = (const float*)d_in[2];   // [16, 3, 64, 64]
  const float* bp  = (const float*)d_in[3];   // [16, 64]
  float* out = (float*)d_out;                 // [64, 2048, 64]

  unsigned short* Ab  = (unsigned short*)d_ws;        // [2048][2048]  8.4 MB
  unsigned short* Y1b = Ab  + (size_t)NN*NN;          // [2048][4096] 16.8 MB (pre-swz)
  unsigned short* Y2b = Y1b + (size_t)NN*JJ;          // [2048][4096] 16.8 MB (pre-swz)
  unsigned short* region = Y2b + (size_t)NN*JJ;       // 50.3 MB shared region
  unsigned short* Xt  = region;                       // [4096][2048] (dead after gemm1)
  unsigned short* Y1T = region + (size_t)JJ*NN;       // [4096][2048] (dead after gemm2)
  unsigned short* Wtg = region;                       // [2048][64][192] (after gemm2)

  supports_kernel<<<NN, 256, 0, stream>>>(emb, Ab);
  xpose_kernel<<<dim3(32, 64), 256, 0, stream>>>(x, Xt);
  dim3 g(512);
  gemm_bt_bf16<<<g, 256, 0, stream>>>(Ab, Xt,  Y1b, Y1T, 1);      // Y1 = A @ X
  gemm_bt_bf16<<<g, 256, 0, stream>>>(Ab, Y1T, Y2b, nullptr, 0);  // Y2 = A @ Y1
  wgen_kernel<<<dim3(256, 3), 256, 0, stream>>>(emb, wp, Wtg);    // overwrites Xt/Y1T
  final_mfma<<<NN, 256, 0, stream>>>(x, emb, bp, Wtg, Y1b, Y2b, out);
}

// Round 11
// 175.862 us; speedup vs baseline: 1.4069x; 1.4069x over previous
//
#include <hip/hip_runtime.h>
#include <hip/hip_bf16.h>

#define BB 64
#define NN 2048
#define CC 64
#define EE 16
#define OO 64
#define JJ 4096  // BB*CC

typedef __attribute__((ext_vector_type(8))) short short8;
typedef __attribute__((ext_vector_type(4))) float f32x4;
typedef __attribute__((ext_vector_type(4))) unsigned short u16x4;
typedef __attribute__((ext_vector_type(8))) unsigned short u16x8;

__device__ __forceinline__ unsigned short f2bf(float f) {
  __hip_bfloat16 h = __float2bfloat16(f);
  return *reinterpret_cast<unsigned short*>(&h);
}
__device__ __forceinline__ float bf2f(unsigned short u) {
  unsigned int v = ((unsigned int)u) << 16;
  return *reinterpret_cast<float*>(&v);
}
__device__ __forceinline__ void gload16(const void* g, void* l) {
  __builtin_amdgcn_global_load_lds(
      (const __attribute__((address_space(1))) unsigned int*)g,
      (__attribute__((address_space(3))) unsigned int*)l, 16, 0, 0);
}

// ---------------- Kernel 1: Ab = bf16(softmax(relu(E E^T), axis=1)) ----------------
__global__ __launch_bounds__(256) void supports_kernel(
    const float* __restrict__ emb, unsigned short* __restrict__ A)
{
  int n = blockIdx.x;
  int tid = threadIdx.x;
  float en[EE];
#pragma unroll
  for (int d = 0; d < EE; ++d) en[d] = emb[n*EE + d];

  float logit[8];
  float lmax = 0.0f;  // relu >= 0
#pragma unroll
  for (int i = 0; i < 8; ++i) {
    int m = i*256 + tid;
    const float* em = emb + m*EE;
    float s = 0.f;
#pragma unroll
    for (int d = 0; d < EE; ++d) s = fmaf(en[d], em[d], s);
    s = fmaxf(s, 0.f);
    logit[i] = s;
    lmax = fmaxf(lmax, s);
  }
  __shared__ float red[256];
  red[tid] = lmax; __syncthreads();
  for (int s = 128; s > 0; s >>= 1) {
    if (tid < s) red[tid] = fmaxf(red[tid], red[tid+s]);
    __syncthreads();
  }
  lmax = red[0]; __syncthreads();
  float sum = 0.f;
#pragma unroll
  for (int i = 0; i < 8; ++i) {
    float e = __expf(logit[i]-lmax);
    logit[i] = e; sum += e;
  }
  red[tid] = sum; __syncthreads();
  for (int s = 128; s > 0; s >>= 1) {
    if (tid < s) red[tid] += red[tid+s];
    __syncthreads();
  }
  float inv = 1.f/red[0];
#pragma unroll
  for (int i = 0; i < 8; ++i) A[(size_t)n*NN + i*256 + tid] = f2bf(logit[i]*inv);
}

// ---------------- Kernel 1b: Xt[b*64+c][n] = bf16(x[b][n][c]) ----------------
__global__ __launch_bounds__(256) void xpose_kernel(
    const float* __restrict__ x, unsigned short* __restrict__ Xt)
{
  int b = blockIdx.y;        // 64
  int n0 = blockIdx.x * 64;  // 32
  __shared__ float T[64][65];
  int tid = threadIdx.x;
  int r = tid >> 4, c4 = (tid & 15) * 4;
  const float* src = x + ((size_t)b*NN + n0)*64;
#pragma unroll
  for (int rr = r; rr < 64; rr += 16) {
    float4 v = *(const float4*)(src + rr*64 + c4);
    T[rr][c4] = v.x; T[rr][c4+1] = v.y; T[rr][c4+2] = v.z; T[rr][c4+3] = v.w;
  }
  __syncthreads();
  int c = tid >> 2, q0 = (tid & 3) * 16;   // 16 bf16 per thread along n
  unsigned short* dst = Xt + ((size_t)b*64 + c)*NN + n0 + q0;
  u16x8 o0, o1;
#pragma unroll
  for (int q = 0; q < 8; ++q) o0[q] = f2bf(T[q0+q][c]);
#pragma unroll
  for (int q = 0; q < 8; ++q) o1[q] = f2bf(T[q0+8+q][c]);
  *(u16x8*)(dst) = o0;
  *(u16x8*)(dst + 8) = o1;
}

// ---------------- Kernel 2: bf16 MFMA GEMM (r6-proven), C[m][j] = sum_k A[m][k]*Bt[j][k] ----
// dbuf LDS + early STAGE + counted vmcnt(8); raw s_barrier.
// Crow stores PRE-SWIZZLED for final_mfma's linear gload16 staging:
//   col' = jcol ^ ((jcol & 0x1C0) >> 3)
__device__ __forceinline__ void stage_tile(
    const unsigned short* __restrict__ A, const unsigned short* __restrict__ Bt,
    unsigned short* as, unsigned short* bs,
    int m0, int j0, int k0, int wid, int lrow, int lu)
{
#pragma unroll
  for (int li = 0; li < 4; ++li) {
    int rb = wid*32 + li*8;
    int r = rb + lrow;
    int su = lu ^ (r & 7);
    gload16(A  + (size_t)(m0 + r)*2048 + k0 + su*8, as + rb*64);
    gload16(Bt + (size_t)(j0 + r)*2048 + k0 + su*8, bs + rb*64);
  }
}

__global__ __launch_bounds__(256) void gemm_bt_bf16(
    const unsigned short* __restrict__ A, const unsigned short* __restrict__ Bt,
    unsigned short* __restrict__ Crow, unsigned short* __restrict__ Ct, int writeT)
{
  __shared__ unsigned short As[2][128*64];  // [row][k], 16B-unit XOR swizzle, dbuf
  __shared__ unsigned short Bs[2][128*64];
  int tid = threadIdx.x;
  int bid = blockIdx.x;
  int swz = (bid & 7) * 64 + (bid >> 3);    // 512 blocks -> XCD-contiguous chunks
  int m0 = (swz >> 5) * 128, j0 = (swz & 31) * 128;
  int wid = tid >> 6, lane = tid & 63;
  int wm = wid >> 1, wn = wid & 1;          // 2x2 wave grid, 64x64 per wave
  int fr = lane & 15, kg = lane >> 4;
  int lrow = lane >> 3, lu = lane & 7;      // staging: 8 rows x 8 units per wave-load

  f32x4 acc[4][4];
#pragma unroll
  for (int i = 0; i < 4; ++i)
#pragma unroll
    for (int j = 0; j < 4; ++j) acc[i][j] = (f32x4){0.f,0.f,0.f,0.f};

  stage_tile(A, Bt, As[0], Bs[0], m0, j0, 0, wid, lrow, lu);

  int cur = 0;
#pragma unroll 2
  for (int k0 = 0; k0 < 2048; k0 += 64) {
    if (k0 + 64 < 2048) {
      stage_tile(A, Bt, As[cur^1], Bs[cur^1], m0, j0, k0 + 64, wid, lrow, lu);
      asm volatile("s_waitcnt vmcnt(8)" ::: "memory");  // prior tile landed; 8 prefetch in flight
    } else {
      asm volatile("s_waitcnt vmcnt(0)" ::: "memory");  // last tile: drain
    }
    __builtin_amdgcn_s_barrier();
    asm volatile("" ::: "memory");

    const unsigned short* asb = As[cur];
    const unsigned short* bsb = Bs[cur];
#pragma unroll
    for (int ks = 0; ks < 2; ++ks) {
      short8 af[4], bv[4];
#pragma unroll
      for (int i = 0; i < 4; ++i) {
        int r = wm*64 + i*16 + fr;
        int u = ((ks << 2) | kg) ^ (r & 7);
        af[i] = *(const short8*)((const char*)asb + r*128 + u*16);
      }
#pragma unroll
      for (int j = 0; j < 4; ++j) {
        int r = wn*64 + j*16 + fr;
        int u = ((ks << 2) | kg) ^ (r & 7);
        bv[j] = *(const short8*)((const char*)bsb + r*128 + u*16);
      }
#pragma unroll
      for (int i = 0; i < 4; ++i)
#pragma unroll
        for (int j = 0; j < 4; ++j)
          acc[i][j] = __builtin_amdgcn_mfma_f32_16x16x32_bf16(af[i], bv[j], acc[i][j], 0, 0, 0);
    }
    asm volatile("" ::: "memory");
    __builtin_amdgcn_s_barrier();
    cur ^= 1;
  }

  int mrow4 = (lane >> 4) * 4;
#pragma unroll
  for (int i = 0; i < 4; ++i) {
    int mbase = m0 + wm*64 + i*16 + mrow4;
#pragma unroll
    for (int j = 0; j < 4; ++j) {
      int jcol = j0 + wn*64 + j*16 + fr;
      f32x4 v = acc[i][j];
      if (writeT) {
        u16x4 pk = { f2bf(v[0]), f2bf(v[1]), f2bf(v[2]), f2bf(v[3]) };
        *(u16x4*)(Ct + (size_t)jcol*2048 + mbase) = pk;
      }
      int jc2 = jcol ^ ((jcol & 0x1C0) >> 3);   // pre-swizzle for final's gload16
      Crow[(size_t)(mbase+0)*4096 + jc2] = f2bf(v[0]);
      Crow[(size_t)(mbase+1)*4096 + jc2] = f2bf(v[1]);
      Crow[(size_t)(mbase+2)*4096 + jc2] = f2bf(v[2]);
      Crow[(size_t)(mbase+3)*4096 + jc2] = f2bf(v[3]);
    }
  }
}

// ---------------- Kernel 3pre: wpt = [W0-W2, W1, 2*W2] (f32, Chebyshev fold) ----------------
// wp flat: d*12288 + kc*64 + o; section r = kc>>6. f+8192 = same d, kc+128.
__global__ __launch_bounds__(256) void wprep_kernel(
    const float* __restrict__ wp, float* __restrict__ wpt)
{
  int f = (blockIdx.x*256 + threadIdx.x) * 4;   // 196608 floats total
  int r = (f % 12288) >> 12;                    // kc>>6
  float4 v = *(const float4*)(wp + f);
  if (r == 0) {
    float4 w2 = *(const float4*)(wp + f + 8192);
    v.x -= w2.x; v.y -= w2.y; v.z -= w2.z; v.w -= w2.w;
  } else if (r == 2) {
    v.x *= 2.f; v.y *= 2.f; v.z *= 2.f; v.w *= 2.f;
  }
  *(float4*)(wpt + f) = v;
}

// ---------------- Kernel 3a: Wtg[n][o][kc'] = bf16(sum_d e[n,d] wpt[d][kc][o]) ----------------
// r5-proven structure: block = (4 nodes, one 64-kc range r); LDS-staged dense 128B runs.
// kc' pre-swizzled: unit u = kc>>3, u' = (u&~7)|((u&7)^(o&7)); elem kc&7 kept.
__global__ __launch_bounds__(256) void wgen_kernel(
    const float* __restrict__ emb, const float* __restrict__ wpt,
    unsigned short* __restrict__ wtg)
{
  __shared__ unsigned short Wlds[4][64*72];  // [node][o*72 + slot*8 + e], 144B rows
  __shared__ float e_s[4][16];
  int tid = threadIdx.x;
  int g = blockIdx.x, r = blockIdx.y;        // g: node group of 4, r: kc range (64 kc)
  int n0 = g*4;
  if (tid < 64) e_s[tid >> 4][tid & 15] = emb[n0*16 + tid];
  __syncthreads();
  int o = tid & 63, w = tid >> 6;
  float e0[16], e1[16], e2[16], e3[16];
#pragma unroll
  for (int d = 0; d < 16; ++d) {
    e0[d] = e_s[0][d]; e1[d] = e_s[1][d]; e2[d] = e_s[2][d]; e3[d] = e_s[3][d];
  }
#pragma unroll
  for (int p = 0; p < 2; ++p) {
    int u = r*8 + p*4 + w;                   // global unit index
    float s0[8], s1[8], s2[8], s3[8];
#pragma unroll
    for (int q = 0; q < 8; ++q) { s0[q]=0.f; s1[q]=0.f; s2[q]=0.f; s3[q]=0.f; }
    const float* wpp = wpt + u*512 + o;      // wpt[d][u*8+q][o]
#pragma unroll
    for (int d = 0; d < 16; ++d) {
#pragma unroll
      for (int q = 0; q < 8; ++q) {
        float wv = wpp[d*12288 + q*64];
        s0[q] = fmaf(e0[d], wv, s0[q]);
        s1[q] = fmaf(e1[d], wv, s1[q]);
        s2[q] = fmaf(e2[d], wv, s2[q]);
        s3[q] = fmaf(e3[d], wv, s3[q]);
      }
    }
    int slot = (u & 7) ^ (o & 7);            // pre-baked final_mfma swizzle
    u16x8 r0, r1, r2, r3;
#pragma unroll
    for (int q = 0; q < 8; ++q) {
      r0[q] = f2bf(s0[q]); r1[q] = f2bf(s1[q]);
      r2[q] = f2bf(s2[q]); r3[q] = f2bf(s3[q]);
    }
    *(u16x8*)&Wlds[0][o*72 + slot*8] = r0;
    *(u16x8*)&Wlds[1][o*72 + slot*8] = r1;
    *(u16x8*)&Wlds[2][o*72 + slot*8] = r2;
    *(u16x8*)&Wlds[3][o*72 + slot*8] = r3;
  }
  __syncthreads();
  // store phase: thread (nd, o) writes one contiguous 128B global run
  int nd = tid >> 6;
  unsigned short* dst = wtg + (size_t)(n0+nd)*12288 + o*192 + r*64;
#pragma unroll
  for (int s = 0; s < 8; ++s)
    *(u16x8*)(dst + s*8) = *(const u16x8*)&Wlds[nd][o*72 + s*8];
}

// ---------------- Kernel 3b: per-node MFMA grouped GEMM (1 node/block, r10-proven) --------
// out[b,n,o] = sum_kc [x | y1 | y2][b][kc] * W'_n[kc][o] + bias_n[o]
__global__ __launch_bounds__(256) void final_mfma(
    const float* __restrict__ x, const float* __restrict__ emb,
    const float* __restrict__ bp, const unsigned short* __restrict__ wtg,
    const unsigned short* __restrict__ y1, const unsigned short* __restrict__ y2,
    float* __restrict__ out)
{
  __shared__ unsigned short As[3*4096];     // 24 KB: [plane][b][64 kc']
  __shared__ unsigned short Ws[12288];      // 24 KB: [o][192 kc']
  int tid = threadIdx.x;
  int lane = tid & 63, wid = tid >> 6;
  int fr = lane & 15, kg = lane >> 4;
  int o = wid*16 + fr;
  int n = blockIdx.x;

  // -- Ws: 6 gload16/thread (Wtg pre-swizzled, linear copy) --
#pragma unroll
  for (int t = 0; t < 6; ++t) {
    int base = wid*3072 + t*512;            // bf16 units, wave-uniform
    gload16(wtg + (size_t)n*12288 + base + lane*8, &Ws[base]);
  }
  // -- As planes 1,2 (y1, y2): 2 gload16/thread each, pre-swizzled source --
#pragma unroll
  for (int t = 0; t < 2; ++t) {
    int base = wid*512 + t*2048;            // covers 0..4095 across 4 waves x 2
    gload16(y1 + (size_t)n*JJ + base + lane*8, &As[4096 + base]);
    gload16(y2 + (size_t)n*JJ + base + lane*8, &As[8192 + base]);
  }
  // -- As plane 0 (x): reg-load f32, cvt, XOR-swizzled ds_write --
  int b = tid & 63, q = tid >> 6;
#pragma unroll
  for (int h = 0; h < 2; ++h) {
    int ul = q + h*4;                       // unit 0..7
    const float* xp = x + ((size_t)b*NN + n)*64 + ul*8;
    float4 v0 = *(const float4*)xp;
    float4 v1 = *(const float4*)(xp + 4);
    float fx[8] = {v0.x,v0.y,v0.z,v0.w,v1.x,v1.y,v1.z,v1.w};
    u16x8 xb;
#pragma unroll
    for (int e = 0; e < 8; ++e) xb[e] = f2bf(fx[e]);
    *(u16x8*)&As[b*64 + (ul ^ (b & 7))*8] = xb;
  }
  __syncthreads();   // drains vmcnt+lgkmcnt (compiler full barrier)

  // -- bias into accumulator init --
  float breg = 0.f;
#pragma unroll
  for (int d = 0; d < 16; ++d) breg = fmaf(emb[n*16 + d], bp[d*64 + o], breg);
  f32x4 acc[4];
#pragma unroll
  for (int k = 0; k < 4; ++k) acc[k] = (f32x4){breg, breg, breg, breg};

  // -- grouped GEMM: M=64(b) x N=16(o per wave) x K=192 --
#pragma unroll
  for (int ks = 0; ks < 6; ++ks) {
    int u = ks*4 + kg;                      // global unit 0..23
    int p = u >> 3, uu = u & 7;
    short8 bv = *(const short8*)&Ws[o*192 + ((u & ~7) | (uu ^ (o & 7)))*8];
#pragma unroll
    for (int k = 0; k < 4; ++k) {
      int ra = k*16 + fr;
      short8 af = *(const short8*)&As[p*4096 + ra*64 + (uu ^ (ra & 7))*8];
      acc[k] = __builtin_amdgcn_mfma_f32_16x16x32_bf16(af, bv, acc[k], 0, 0, 0);
    }
  }
  // -- epilogue: col=lane&15 -> o, row=(lane>>4)*4+reg -> b --
  int mrow = (lane >> 4) * 4;
#pragma unroll
  for (int k = 0; k < 4; ++k) {
#pragma unroll
    for (int rr = 0; rr < 4; ++rr) {
      int brow = k*16 + mrow + rr;
      out[((size_t)brow*NN + n)*64 + o] = acc[k][rr];
    }
  }
}

extern "C" void kernel_launch(void* const* d_in, const int* in_sizes, int n_in,
                              void* d_out, int out_size, void* d_ws, size_t ws_size,
                              hipStream_t stream) {
  const float* x   = (const float*)d_in[0];   // [64, 2048, 64]
  const float* emb = (const float*)d_in[1];   // [2048, 16]
  const float* wp  = (const float*)d_in[2];   // [16, 3, 64, 64]
  const float* bp  = (const float*)d_in[3];   // [16, 64]
  float* out = (float*)d_out;                 // [64, 2048, 64]

  unsigned short* Ab  = (unsigned short*)d_ws;        // [2048][2048]  8.4 MB
  unsigned short* Y1b = Ab  + (size_t)NN*NN;          // [2048][4096] 16.8 MB (pre-swz)
  unsigned short* Y2b = Y1b + (size_t)NN*JJ;          // [2048][4096] 16.8 MB (pre-swz)
  unsigned short* region = Y2b + (size_t)NN*JJ;       // 50.3 MB shared region
  unsigned short* Xt  = region;                       // [4096][2048] (dead after gemm1)
  unsigned short* Y1T = region + (size_t)JJ*NN;       // [4096][2048] (dead after gemm2)
  unsigned short* Wtg = region;                       // [2048][64][192] (after gemm2)
  float* Wpt = (float*)(region + (size_t)NN*64*192);  // [16][3][64][64] f32 0.8 MB

  supports_kernel<<<NN, 256, 0, stream>>>(emb, Ab);
  xpose_kernel<<<dim3(32, 64), 256, 0, stream>>>(x, Xt);
  wprep_kernel<<<192, 256, 0, stream>>>(wp, Wpt);                 // fold into pool
  dim3 g(512);
  gemm_bt_bf16<<<g, 256, 0, stream>>>(Ab, Xt,  Y1b, Y1T, 1);      // Y1 = A @ X
  gemm_bt_bf16<<<g, 256, 0, stream>>>(Ab, Y1T, Y2b, nullptr, 0);  // Y2 = A @ Y1
  wgen_kernel<<<dim3(512, 3), 256, 0, stream>>>(emb, Wpt, Wtg);   // overwrites Xt/Y1T
  final_mfma<<<NN, 256, 0, stream>>>(x, emb, bp, Wtg, Y1b, Y2b, out);
}

// Round 12
// 175.245 us; speedup vs baseline: 1.4119x; 1.0035x over previous
//
#include <hip/hip_runtime.h>
#include <hip/hip_bf16.h>

#define BB 64
#define NN 2048
#define CC 64
#define EE 16
#define OO 64
#define JJ 4096  // BB*CC

typedef __attribute__((ext_vector_type(8))) short short8;
typedef __attribute__((ext_vector_type(4))) float f32x4;
typedef __attribute__((ext_vector_type(4))) unsigned short u16x4;
typedef __attribute__((ext_vector_type(8))) unsigned short u16x8;

__device__ __forceinline__ unsigned short f2bf(float f) {
  __hip_bfloat16 h = __float2bfloat16(f);
  return *reinterpret_cast<unsigned short*>(&h);
}
__device__ __forceinline__ float bf2f(unsigned short u) {
  unsigned int v = ((unsigned int)u) << 16;
  return *reinterpret_cast<float*>(&v);
}
__device__ __forceinline__ void gload16(const void* g, void* l) {
  __builtin_amdgcn_global_load_lds(
      (const __attribute__((address_space(1))) unsigned int*)g,
      (__attribute__((address_space(3))) unsigned int*)l, 16, 0, 0);
}

// ---------------- Kernel 1 (fused pre-pass): supports | xpose | wprep ----------------
// blocks [0,2048):    Ab[n][:] = bf16(softmax(relu(E E^T))[n])
// blocks [2048,4096): Xt[b*64+c][n] = bf16(x[b][n][c])
// blocks [4096,4288): wpt = [W0-W2, W1, 2*W2]  (f32 Chebyshev fold)
__global__ __launch_bounds__(256) void prep_kernel(
    const float* __restrict__ emb, const float* __restrict__ x,
    const float* __restrict__ wp,
    unsigned short* __restrict__ A, unsigned short* __restrict__ Xt,
    float* __restrict__ wpt)
{
  __shared__ float T[64][65];
  __shared__ float red[256];
  int tid = threadIdx.x;
  int bx = blockIdx.x;

  if (bx < 2048) {                       // ---- supports ----
    int n = bx;
    float en[EE];
#pragma unroll
    for (int d = 0; d < EE; ++d) en[d] = emb[n*EE + d];
    float logit[8];
    float lmax = 0.0f;  // relu >= 0
#pragma unroll
    for (int i = 0; i < 8; ++i) {
      int m = i*256 + tid;
      const float* em = emb + m*EE;
      float s = 0.f;
#pragma unroll
      for (int d = 0; d < EE; ++d) s = fmaf(en[d], em[d], s);
      s = fmaxf(s, 0.f);
      logit[i] = s;
      lmax = fmaxf(lmax, s);
    }
    red[tid] = lmax; __syncthreads();
    for (int s = 128; s > 0; s >>= 1) {
      if (tid < s) red[tid] = fmaxf(red[tid], red[tid+s]);
      __syncthreads();
    }
    lmax = red[0]; __syncthreads();
    float sum = 0.f;
#pragma unroll
    for (int i = 0; i < 8; ++i) {
      float e = __expf(logit[i]-lmax);
      logit[i] = e; sum += e;
    }
    red[tid] = sum; __syncthreads();
    for (int s = 128; s > 0; s >>= 1) {
      if (tid < s) red[tid] += red[tid+s];
      __syncthreads();
    }
    float inv = 1.f/red[0];
#pragma unroll
    for (int i = 0; i < 8; ++i) A[(size_t)n*NN + i*256 + tid] = f2bf(logit[i]*inv);

  } else if (bx < 4096) {                // ---- xpose ----
    int bx2 = bx - 2048;
    int b = bx2 >> 5;                    // 64
    int n0 = (bx2 & 31) * 64;            // 32
    int r = tid >> 4, c4 = (tid & 15) * 4;
    const float* src = x + ((size_t)b*NN + n0)*64;
#pragma unroll
    for (int rr = r; rr < 64; rr += 16) {
      float4 v = *(const float4*)(src + rr*64 + c4);
      T[rr][c4] = v.x; T[rr][c4+1] = v.y; T[rr][c4+2] = v.z; T[rr][c4+3] = v.w;
    }
    __syncthreads();
    int c = tid >> 2, q0 = (tid & 3) * 16;
    unsigned short* dst = Xt + ((size_t)b*64 + c)*NN + n0 + q0;
    u16x8 o0, o1;
#pragma unroll
    for (int q = 0; q < 8; ++q) o0[q] = f2bf(T[q0+q][c]);
#pragma unroll
    for (int q = 0; q < 8; ++q) o1[q] = f2bf(T[q0+8+q][c]);
    *(u16x8*)(dst) = o0;
    *(u16x8*)(dst + 8) = o1;

  } else {                               // ---- wprep ----
    int f = ((bx - 4096)*256 + tid) * 4; // 196608 floats total
    int r = (f % 12288) >> 12;           // kc>>6
    float4 v = *(const float4*)(wp + f);
    if (r == 0) {
      float4 w2 = *(const float4*)(wp + f + 8192);
      v.x -= w2.x; v.y -= w2.y; v.z -= w2.z; v.w -= w2.w;
    } else if (r == 2) {
      v.x *= 2.f; v.y *= 2.f; v.z *= 2.f; v.w *= 2.f;
    }
    *(float4*)(wpt + f) = v;
  }
}

// ---------------- Kernel 2: bf16 MFMA GEMM (r6-proven), C[m][j] = sum_k A[m][k]*Bt[j][k] ----
// dbuf LDS + early STAGE + counted vmcnt(8); raw s_barrier.
// Crow stores PRE-SWIZZLED for final_mfma's linear gload16 staging:
//   col' = jcol ^ ((jcol & 0x1C0) >> 3)
__device__ __forceinline__ void stage_tile(
    const unsigned short* __restrict__ A, const unsigned short* __restrict__ Bt,
    unsigned short* as, unsigned short* bs,
    int m0, int j0, int k0, int wid, int lrow, int lu)
{
#pragma unroll
  for (int li = 0; li < 4; ++li) {
    int rb = wid*32 + li*8;
    int r = rb + lrow;
    int su = lu ^ (r & 7);
    gload16(A  + (size_t)(m0 + r)*2048 + k0 + su*8, as + rb*64);
    gload16(Bt + (size_t)(j0 + r)*2048 + k0 + su*8, bs + rb*64);
  }
}

__global__ __launch_bounds__(256) void gemm_bt_bf16(
    const unsigned short* __restrict__ A, const unsigned short* __restrict__ Bt,
    unsigned short* __restrict__ Crow, unsigned short* __restrict__ Ct, int writeT)
{
  __shared__ unsigned short As[2][128*64];  // [row][k], 16B-unit XOR swizzle, dbuf
  __shared__ unsigned short Bs[2][128*64];
  int tid = threadIdx.x;
  int bid = blockIdx.x;
  int swz = (bid & 7) * 64 + (bid >> 3);    // 512 blocks -> XCD-contiguous chunks
  int m0 = (swz >> 5) * 128, j0 = (swz & 31) * 128;
  int wid = tid >> 6, lane = tid & 63;
  int wm = wid >> 1, wn = wid & 1;          // 2x2 wave grid, 64x64 per wave
  int fr = lane & 15, kg = lane >> 4;
  int lrow = lane >> 3, lu = lane & 7;      // staging: 8 rows x 8 units per wave-load

  f32x4 acc[4][4];
#pragma unroll
  for (int i = 0; i < 4; ++i)
#pragma unroll
    for (int j = 0; j < 4; ++j) acc[i][j] = (f32x4){0.f,0.f,0.f,0.f};

  stage_tile(A, Bt, As[0], Bs[0], m0, j0, 0, wid, lrow, lu);

  int cur = 0;
#pragma unroll 2
  for (int k0 = 0; k0 < 2048; k0 += 64) {
    if (k0 + 64 < 2048) {
      stage_tile(A, Bt, As[cur^1], Bs[cur^1], m0, j0, k0 + 64, wid, lrow, lu);
      asm volatile("s_waitcnt vmcnt(8)" ::: "memory");  // prior tile landed; 8 prefetch in flight
    } else {
      asm volatile("s_waitcnt vmcnt(0)" ::: "memory");  // last tile: drain
    }
    __builtin_amdgcn_s_barrier();
    asm volatile("" ::: "memory");

    const unsigned short* asb = As[cur];
    const unsigned short* bsb = Bs[cur];
#pragma unroll
    for (int ks = 0; ks < 2; ++ks) {
      short8 af[4], bv[4];
#pragma unroll
      for (int i = 0; i < 4; ++i) {
        int r = wm*64 + i*16 + fr;
        int u = ((ks << 2) | kg) ^ (r & 7);
        af[i] = *(const short8*)((const char*)asb + r*128 + u*16);
      }
#pragma unroll
      for (int j = 0; j < 4; ++j) {
        int r = wn*64 + j*16 + fr;
        int u = ((ks << 2) | kg) ^ (r & 7);
        bv[j] = *(const short8*)((const char*)bsb + r*128 + u*16);
      }
#pragma unroll
      for (int i = 0; i < 4; ++i)
#pragma unroll
        for (int j = 0; j < 4; ++j)
          acc[i][j] = __builtin_amdgcn_mfma_f32_16x16x32_bf16(af[i], bv[j], acc[i][j], 0, 0, 0);
    }
    asm volatile("" ::: "memory");
    __builtin_amdgcn_s_barrier();
    cur ^= 1;
  }

  int mrow4 = (lane >> 4) * 4;
#pragma unroll
  for (int i = 0; i < 4; ++i) {
    int mbase = m0 + wm*64 + i*16 + mrow4;
#pragma unroll
    for (int j = 0; j < 4; ++j) {
      int jcol = j0 + wn*64 + j*16 + fr;
      f32x4 v = acc[i][j];
      if (writeT) {
        u16x4 pk = { f2bf(v[0]), f2bf(v[1]), f2bf(v[2]), f2bf(v[3]) };
        *(u16x4*)(Ct + (size_t)jcol*2048 + mbase) = pk;
      }
      int jc2 = jcol ^ ((jcol & 0x1C0) >> 3);   // pre-swizzle for final's gload16
      Crow[(size_t)(mbase+0)*4096 + jc2] = f2bf(v[0]);
      Crow[(size_t)(mbase+1)*4096 + jc2] = f2bf(v[1]);
      Crow[(size_t)(mbase+2)*4096 + jc2] = f2bf(v[2]);
      Crow[(size_t)(mbase+3)*4096 + jc2] = f2bf(v[3]);
    }
  }
}

// ---------------- Kernel 3a: Wtg[n][o][kc'] = bf16(sum_d e[n,d] wpt[d][kc][o]) ----------------
// 8 nodes/block (wpt value loaded once -> 8 FMA targets): halves wpt L2 traffic.
// kc' pre-swizzled: unit u = kc>>3, u' = (u&~7)|((u&7)^(o&7)); elem kc&7 kept.
// LDS-staged store phase: dense 128B global runs per (n,o).
__global__ __launch_bounds__(256) void wgen_kernel(
    const float* __restrict__ emb, const float* __restrict__ wpt,
    unsigned short* __restrict__ wtg)
{
  __shared__ unsigned short Wlds[8][64*72];  // 72 KB: [node][o*72 + slot*8 + e]
  __shared__ float e_s[8][16];
  int tid = threadIdx.x;
  int g = blockIdx.x, r = blockIdx.y;        // g: node group of 8, r: kc range (64 kc)
  int n0 = g*8;
  if (tid < 128) e_s[tid >> 4][tid & 15] = emb[n0*16 + tid];
  __syncthreads();
  int o = tid & 63, w = tid >> 6;
#pragma unroll 1
  for (int p = 0; p < 2; ++p) {
    int u = r*8 + p*4 + w;                   // global unit index
    float acc[8][8];                         // [node][q], all statically indexed
#pragma unroll
    for (int n = 0; n < 8; ++n)
#pragma unroll
      for (int q = 0; q < 8; ++q) acc[n][q] = 0.f;
    const float* wpp = wpt + u*512 + o;      // wpt[d][u*8+q][o]
#pragma unroll
    for (int d = 0; d < 16; ++d) {
      float wv[8];
#pragma unroll
      for (int q = 0; q < 8; ++q) wv[q] = wpp[d*12288 + q*64];
#pragma unroll
      for (int n = 0; n < 8; ++n) {
        float en = e_s[n][d];
#pragma unroll
        for (int q = 0; q < 8; ++q) acc[n][q] = fmaf(en, wv[q], acc[n][q]);
      }
    }
    int slot = (u & 7) ^ (o & 7);            // pre-baked final_mfma swizzle
#pragma unroll
    for (int n = 0; n < 8; ++n) {
      u16x8 pk;
#pragma unroll
      for (int q = 0; q < 8; ++q) pk[q] = f2bf(acc[n][q]);
      *(u16x8*)&Wlds[n][o*72 + slot*8] = pk;
    }
  }
  __syncthreads();
  // store phase: thread (nd, o) writes one contiguous 128B global run; 2 halves
#pragma unroll
  for (int half = 0; half < 2; ++half) {
    int nd = half*4 + (tid >> 6);
    unsigned short* dst = wtg + (size_t)(n0+nd)*12288 + o*192 + r*64;
#pragma unroll
    for (int s = 0; s < 8; ++s)
      *(u16x8*)(dst + s*8) = *(const u16x8*)&Wlds[nd][o*72 + s*8];
  }
}

// ---------------- Kernel 3b: per-node MFMA grouped GEMM (1 node/block, r10-proven) --------
// out[b,n,o] = sum_kc [x | y1 | y2][b][kc] * W'_n[kc][o] + bias_n[o]
__global__ __launch_bounds__(256) void final_mfma(
    const float* __restrict__ x, const float* __restrict__ emb,
    const float* __restrict__ bp, const unsigned short* __restrict__ wtg,
    const unsigned short* __restrict__ y1, const unsigned short* __restrict__ y2,
    float* __restrict__ out)
{
  __shared__ unsigned short As[3*4096];     // 24 KB: [plane][b][64 kc']
  __shared__ unsigned short Ws[12288];      // 24 KB: [o][192 kc']
  int tid = threadIdx.x;
  int lane = tid & 63, wid = tid >> 6;
  int fr = lane & 15, kg = lane >> 4;
  int o = wid*16 + fr;
  int n = blockIdx.x;

  // -- Ws: 6 gload16/thread (Wtg pre-swizzled, linear copy) --
#pragma unroll
  for (int t = 0; t < 6; ++t) {
    int base = wid*3072 + t*512;            // bf16 units, wave-uniform
    gload16(wtg + (size_t)n*12288 + base + lane*8, &Ws[base]);
  }
  // -- As planes 1,2 (y1, y2): 2 gload16/thread each, pre-swizzled source --
#pragma unroll
  for (int t = 0; t < 2; ++t) {
    int base = wid*512 + t*2048;            // covers 0..4095 across 4 waves x 2
    gload16(y1 + (size_t)n*JJ + base + lane*8, &As[4096 + base]);
    gload16(y2 + (size_t)n*JJ + base + lane*8, &As[8192 + base]);
  }
  // -- As plane 0 (x): reg-load f32, cvt, XOR-swizzled ds_write --
  int b = tid & 63, q = tid >> 6;
#pragma unroll
  for (int h = 0; h < 2; ++h) {
    int ul = q + h*4;                       // unit 0..7
    const float* xp = x + ((size_t)b*NN + n)*64 + ul*8;
    float4 v0 = *(const float4*)xp;
    float4 v1 = *(const float4*)(xp + 4);
    float fx[8] = {v0.x,v0.y,v0.z,v0.w,v1.x,v1.y,v1.z,v1.w};
    u16x8 xb;
#pragma unroll
    for (int e = 0; e < 8; ++e) xb[e] = f2bf(fx[e]);
    *(u16x8*)&As[b*64 + (ul ^ (b & 7))*8] = xb;
  }
  __syncthreads();   // drains vmcnt+lgkmcnt (compiler full barrier)

  // -- bias into accumulator init --
  float breg = 0.f;
#pragma unroll
  for (int d = 0; d < 16; ++d) breg = fmaf(emb[n*16 + d], bp[d*64 + o], breg);
  f32x4 acc[4];
#pragma unroll
  for (int k = 0; k < 4; ++k) acc[k] = (f32x4){breg, breg, breg, breg};

  // -- grouped GEMM: M=64(b) x N=16(o per wave) x K=192 --
#pragma unroll
  for (int ks = 0; ks < 6; ++ks) {
    int u = ks*4 + kg;                      // global unit 0..23
    int p = u >> 3, uu = u & 7;
    short8 bv = *(const short8*)&Ws[o*192 + ((u & ~7) | (uu ^ (o & 7)))*8];
#pragma unroll
    for (int k = 0; k < 4; ++k) {
      int ra = k*16 + fr;
      short8 af = *(const short8*)&As[p*4096 + ra*64 + (uu ^ (ra & 7))*8];
      acc[k] = __builtin_amdgcn_mfma_f32_16x16x32_bf16(af, bv, acc[k], 0, 0, 0);
    }
  }
  // -- epilogue: col=lane&15 -> o, row=(lane>>4)*4+reg -> b --
  int mrow = (lane >> 4) * 4;
#pragma unroll
  for (int k = 0; k < 4; ++k) {
#pragma unroll
    for (int rr = 0; rr < 4; ++rr) {
      int brow = k*16 + mrow + rr;
      out[((size_t)brow*NN + n)*64 + o] = acc[k][rr];
    }
  }
}

extern "C" void kernel_launch(void* const* d_in, const int* in_sizes, int n_in,
                              void* d_out, int out_size, void* d_ws, size_t ws_size,
                              hipStream_t stream) {
  const float* x   = (const float*)d_in[0];   // [64, 2048, 64]
  const float* emb = (const float*)d_in[1];   // [2048, 16]
  const float* wp  = (const float*)d_in[2];   // [16, 3, 64, 64]
  const float* bp  = (const float*)d_in[3];   // [16, 64]
  float* out = (float*)d_out;                 // [64, 2048, 64]

  unsigned short* Ab  = (unsigned short*)d_ws;        // [2048][2048]  8.4 MB
  unsigned short* Y1b = Ab  + (size_t)NN*NN;          // [2048][4096] 16.8 MB (pre-swz)
  unsigned short* Y2b = Y1b + (size_t)NN*JJ;          // [2048][4096] 16.8 MB (pre-swz)
  unsigned short* region = Y2b + (size_t)NN*JJ;       // 50.3 MB shared region
  unsigned short* Xt  = region;                       // [4096][2048] (dead after gemm1)
  unsigned short* Y1T = region + (size_t)JJ*NN;       // [4096][2048] (dead after gemm2)
  unsigned short* Wtg = region;                       // [2048][64][192] (after gemm2)
  float* Wpt = (float*)(region + (size_t)NN*64*192);  // [16][3][64][64] f32 0.8 MB

  prep_kernel<<<4288, 256, 0, stream>>>(emb, x, wp, Ab, Xt, Wpt);
  dim3 g(512);
  gemm_bt_bf16<<<g, 256, 0, stream>>>(Ab, Xt,  Y1b, Y1T, 1);      // Y1 = A @ X
  gemm_bt_bf16<<<g, 256, 0, stream>>>(Ab, Y1T, Y2b, nullptr, 0);  // Y2 = A @ Y1
  wgen_kernel<<<dim3(256, 3), 256, 0, stream>>>(emb, Wpt, Wtg);   // overwrites Xt/Y1T
  final_mfma<<<NN, 256, 0, stream>>>(x, emb, bp, Wtg, Y1b, Y2b, out);
}